// Round 2
// 123.439 us; speedup vs baseline: 1.0116x; 1.0116x over previous
//
#include <hip/hip_runtime.h>

// ConvCaps (Matrix Capsules w/ EM routing), MI355X fp32 implementation.
// One block per output position (b, oi, oj): 784 blocks x 256 threads.
//
// v2 (resubmit — round-1 bench hit GPUAcquisitionTimeout, no data):
// fuse E-step + following M-step into ONE vote pass.
// The per-n softmax is over classes only, so after computing v[n][c] once we
// can form ln_ap, softmax across the 32 classes (shfl over lane-bits 0..2 +
// a tiny cross-wave LDS combine), get r immediately, and accumulate the next
// M-step's sums UNNORMALIZED (divide by r_sum+EPS at the end — identical to
// coeff = r/(r_sum+EPS) applied per term). Votes: 3 passes -> 2 for iters=2.
// sR (19KB, main bank-conflict source) is gone: M0 uses r = a_in/32 straight
// from sA; fused-pass r lives in registers. sP rows padded 16->20 floats so
// the 8 sub-lanes' ds_read_b128 hit 8 disjoint bank quads.

namespace {

constexpr int OHW  = 14;
constexpr int NPOS = 4 * OHW * OHW;     // 784
constexpr int NN   = 144;               // K*K*B = 3*3*16
constexpr int CC   = 32;
constexpr float LAMB  = 0.01f;
constexpr float EPSF  = 1e-6f;
constexpr float LN2PI = 1.8378770664093453f;
constexpr int PSTR = 20;                // sP row stride (floats): 20*sub mod 32 distinct per sub

__device__ __forceinline__ void mat44(const float4 pr[4], const float4 wr[4], float v[16]) {
  #pragma unroll
  for (int i = 0; i < 4; ++i) {
    v[4*i+0] = fmaf(pr[i].x, wr[0].x, fmaf(pr[i].y, wr[1].x, fmaf(pr[i].z, wr[2].x, pr[i].w * wr[3].x)));
    v[4*i+1] = fmaf(pr[i].x, wr[0].y, fmaf(pr[i].y, wr[1].y, fmaf(pr[i].z, wr[2].y, pr[i].w * wr[3].y)));
    v[4*i+2] = fmaf(pr[i].x, wr[0].z, fmaf(pr[i].y, wr[1].z, fmaf(pr[i].z, wr[2].z, pr[i].w * wr[3].z)));
    v[4*i+3] = fmaf(pr[i].x, wr[0].w, fmaf(pr[i].y, wr[1].w, fmaf(pr[i].z, wr[2].w, pr[i].w * wr[3].w)));
  }
}

__global__ __launch_bounds__(256)
void convcaps_em(const float* __restrict__ x,
                 const float* __restrict__ a,
                 const float* __restrict__ w,        // (144, 32, 4, 4)
                 const float* __restrict__ beta_u,   // (32,1)
                 const float* __restrict__ beta_a,   // (32,1)
                 const int*   __restrict__ iters_p,
                 float* __restrict__ out_mu,         // (4,14,14,32,16)
                 float* __restrict__ out_a)          // (4,14,14,32,1)
{
  __shared__ __align__(16) float sP[NN * PSTR];   // pose patch, padded rows
  __shared__ float  sA[NN];                       // input activations
  __shared__ float2 sMB[2][4][8];                 // softmax partials [parity][wave][sub] = {max, sum}

  const int tid = threadIdx.x;
  const int pos = blockIdx.x;
  const int b   = pos / (OHW * OHW);
  const int rem = pos - b * (OHW * OHW);
  const int oi  = rem / OHW;
  const int oj  = rem - oi * OHW;

  int iters = iters_p[0];
  iters = (iters < 1) ? 1 : (iters > 16 ? 16 : iters);

  // ---- stage pose patch + activations ----
  // n = (kh*3+kw)*16 + bc maps to x[b, oi+kh, oj+kw, bc, :]
  #pragma unroll
  for (int t = 0; t < 9; ++t) {
    const int kh = t / 3, kw = t % 3;
    const int idx = t * 256 + tid;              // 0..2303 = n*16 + p
    const float val = x[(((b * 16 + oi + kh) * 16) + (oj + kw)) * 256 + tid];
    sP[(idx >> 4) * PSTR + (idx & 15)] = val;
  }
  if (tid < NN) {
    const int kh = tid / 48, kw = (tid >> 4) % 3, bc = tid & 15;
    sA[tid] = a[(((b * 16 + oi + kh) * 16) + (oj + kw)) * 16 + bc];
  }
  __syncthreads();

  // thread map: octets of consecutive lanes own consecutive classes;
  // sub (n-slice) lives in lane bits 3..5 so M-reduction is shfl_xor 8/16/32;
  // class lives in lane bits 0..2 (+wave) so softmax is shfl_xor 1/2/4 + LDS.
  const int lane = tid & 63;
  const int wv   = tid >> 6;
  const int c    = wv * 8 + (lane & 7);     // 0..31
  const int sub  = lane >> 3;               // 0..7
  const float bu16 = 16.0f * beta_u[c];
  const float ba   = beta_a[c];

  // ---- iteration 0 M-step: r = a_in/32 (uniform over classes), no sR needed ----
  float rs = 0.f;
  #pragma unroll
  for (int k = 0; k < 18; ++k) rs += sA[sub + 8 * k];
  rs += __shfl_xor(rs, 8);
  rs += __shfl_xor(rs, 16);
  rs += __shfl_xor(rs, 32);
  rs *= (1.0f / CC);                                  // r_sum (same for every class)
  const float cw = 1.0f / (CC * (rs + EPSF));         // coeff[n] = sA[n] * cw

  float S0 = 0.f, S1[16], S2[16];
  #pragma unroll
  for (int p = 0; p < 16; ++p) { S1[p] = 0.f; S2[p] = 0.f; }

  for (int k = 0; k < 18; ++k) {
    const int n = sub + 8 * k;
    const float4* Pp = (const float4*)(sP + n * PSTR);
    const float4 pr[4] = {Pp[0], Pp[1], Pp[2], Pp[3]};
    const float4* Wp = (const float4*)(w + n * 512 + c * 16);
    const float4 wr[4] = {Wp[0], Wp[1], Wp[2], Wp[3]};
    float v[16];
    mat44(pr, wr, v);
    const float coeff = sA[n] * cw;
    S0 += coeff;
    #pragma unroll
    for (int p = 0; p < 16; ++p) {
      S1[p] = fmaf(coeff, v[p], S1[p]);
      S2[p] = fmaf(coeff * v[p], v[p], S2[p]);
    }
  }
  #pragma unroll
  for (int m = 8; m <= 32; m <<= 1) {
    S0 += __shfl_xor(S0, m);
    #pragma unroll
    for (int p = 0; p < 16; ++p) {
      S1[p] += __shfl_xor(S1[p], m);
      S2[p] += __shfl_xor(S2[p], m);
    }
  }

  // per-class stats (coeff was pre-normalized, so mu = S1 directly)
  float mu[16], hi[16];
  float logsum = 0.f;
  #pragma unroll
  for (int p = 0; p < 16; ++p) {
    mu[p] = S1[p];
    float sig = S2[p] - mu[p] * (2.0f * S1[p] - mu[p] * S0) + EPSF;
    sig = fmaxf(sig, 1e-12f);
    logsum += __logf(sig);
    hi[p] = 0.5f / sig;
  }
  float cost = rs * (bu16 + 0.5f * logsum);
  float aout = 1.0f / (1.0f + __expf(-LAMB * (ba - cost)));

  // ---- fused E + M passes: one vote computation serves both ----
  for (int it = 1; it < iters; ++it) {
    const float kc = __logf(aout + EPSF) - 0.5f * logsum - 8.0f * LN2PI;
    float T0 = 0.f, T1[16], T2[16];
    #pragma unroll
    for (int p = 0; p < 16; ++p) { T1[p] = 0.f; T2[p] = 0.f; }

    // prefetch chunk-0 weights
    const float4* W0 = (const float4*)(w + sub * 512 + c * 16);
    float4 wr[4] = {W0[0], W0[1], W0[2], W0[3]};

    #pragma unroll 1
    for (int ch = 0; ch < 18; ++ch) {
      const int n = sub + 8 * ch;
      const float4* Pp = (const float4*)(sP + n * PSTR);
      const float4 pr[4] = {Pp[0], Pp[1], Pp[2], Pp[3]};
      float v[16];
      mat44(pr, wr, v);
      // issue next chunk's w-loads now; latency hides under softmax+barrier
      if (ch < 17) {
        const float4* Wn = (const float4*)(w + (n + 8) * 512 + c * 16);
        wr[0] = Wn[0]; wr[1] = Wn[1]; wr[2] = Wn[2]; wr[3] = Wn[3];
      }
      // ln_ap for this (n, c)
      float s = 0.f;
      #pragma unroll
      for (int p = 0; p < 16; ++p) {
        const float d = v[p] - mu[p];
        s = fmaf(d * d, hi[p], s);
      }
      const float xv = kc - s;
      // softmax over classes: intra-wave partial over the 8 c-lanes...
      float m8 = xv;
      m8 = fmaxf(m8, __shfl_xor(m8, 1));
      m8 = fmaxf(m8, __shfl_xor(m8, 2));
      m8 = fmaxf(m8, __shfl_xor(m8, 4));
      const float e = __expf(xv - m8);
      float z8 = e;
      z8 += __shfl_xor(z8, 1);
      z8 += __shfl_xor(z8, 2);
      z8 += __shfl_xor(z8, 4);
      // ...then combine the 4 waves' partials through LDS (double-buffered)
      const int par = (it * 18 + ch) & 1;
      if ((lane & 7) == 0) sMB[par][wv][sub] = make_float2(m8, z8);
      __syncthreads();
      const float2 q0 = sMB[par][0][sub];
      const float2 q1 = sMB[par][1][sub];
      const float2 q2 = sMB[par][2][sub];
      const float2 q3 = sMB[par][3][sub];
      const float M = fmaxf(fmaxf(q0.x, q1.x), fmaxf(q2.x, q3.x));
      const float Z = fmaf(q0.y, __expf(q0.x - M),
                      fmaf(q1.y, __expf(q1.x - M),
                      fmaf(q2.y, __expf(q2.x - M),
                           q3.y * __expf(q3.x - M))));
      // r[n][c] = a_in[n] * softmax_c(ln_ap); accumulate UNNORMALIZED sums
      const float rn = sA[n] * e * __expf(m8 - M) * __builtin_amdgcn_rcpf(Z);
      T0 += rn;
      #pragma unroll
      for (int p = 0; p < 16; ++p) {
        T1[p] = fmaf(rn, v[p], T1[p]);
        T2[p] = fmaf(rn * v[p], v[p], T2[p]);
      }
    }
    #pragma unroll
    for (int m = 8; m <= 32; m <<= 1) {
      T0 += __shfl_xor(T0, m);
      #pragma unroll
      for (int p = 0; p < 16; ++p) {
        T1[p] += __shfl_xor(T1[p], m);
        T2[p] += __shfl_xor(T2[p], m);
      }
    }
    // stats from unnormalized sums: mu = T1/(T0+eps), sig = sum r(v-mu)^2/(T0+eps)+eps
    const float inv1 = 1.0f / (T0 + EPSF);
    logsum = 0.f;
    #pragma unroll
    for (int p = 0; p < 16; ++p) {
      mu[p] = T1[p] * inv1;
      float sig = fmaf(mu[p], fmaf(mu[p], T0, -2.0f * T1[p]), T2[p]) * inv1 + EPSF;
      sig = fmaxf(sig, 1e-12f);
      logsum += __logf(sig);
      hi[p] = 0.5f / sig;
    }
    cost = T0 * (bu16 + 0.5f * logsum);   // r_sum = T0 exactly
    aout = 1.0f / (1.0f + __expf(-LAMB * (ba - cost)));
  }

  // ---- epilogue ----
  if (sub == 0) {
    float4* om = (float4*)(out_mu + (size_t)pos * 512 + c * 16);
    om[0] = make_float4(mu[0],  mu[1],  mu[2],  mu[3]);
    om[1] = make_float4(mu[4],  mu[5],  mu[6],  mu[7]);
    om[2] = make_float4(mu[8],  mu[9],  mu[10], mu[11]);
    om[3] = make_float4(mu[12], mu[13], mu[14], mu[15]);
    out_a[pos * CC + c] = aout;
  }
}

} // namespace

extern "C" void kernel_launch(void* const* d_in, const int* in_sizes, int n_in,
                              void* d_out, int out_size, void* d_ws, size_t ws_size,
                              hipStream_t stream) {
  const float* x  = (const float*)d_in[0];
  const float* a  = (const float*)d_in[1];
  const float* w  = (const float*)d_in[2];
  const float* bu = (const float*)d_in[3];
  const float* ba = (const float*)d_in[4];
  const int* iters = (const int*)d_in[5];

  float* out_mu = (float*)d_out;                       // 4*14*14*32*16 = 401408
  float* out_a  = out_mu + (size_t)NPOS * CC * 16;     // + 4*14*14*32  =  25088

  convcaps_em<<<NPOS, 256, 0, stream>>>(x, a, w, bu, ba, iters, out_mu, out_a);
}

// Round 3
// 121.935 us; speedup vs baseline: 1.0240x; 1.0123x over previous
//
#include <hip/hip_runtime.h>

// ConvCaps (Matrix Capsules w/ EM routing), MI355X fp32 implementation.
// One block per output position (b, oi, oj): 784 blocks x 256 threads.
//
// v3: barrier-free chunk loop via remapped lanes.
// c = lane&31 puts all 32 classes of a vote row n in one half-wave, so the
// E-step softmax over classes is 5 shfl_xor + 1 exp, no LDS, no barrier
// (v2 had a __syncthreads per chunk = 18/pass). The M-reduction over the 8
// n-slices moves to a once-per-pass LDS reduce (2 barriers total per pass).
// Iteration 0 uses the same unnormalized-sum path as the fused passes
// (rn = a_in, inv = 1/(U0+32*EPS), r_sum = U0/32 — algebraically identical
// to the reference's coeff = r/(r_sum+EPS) with r = a_in/32).
// ln_p quadratic expanded: s = sum_p v*(hi*v + hm), hm = -2*hi*mu, with the
// constant sum(hi*mu^2) folded into kc — 16 fewer VALU/chunk, mu not live
// in the chunk loop.

namespace {

constexpr int OHW  = 14;
constexpr int NPOS = 4 * OHW * OHW;     // 784
constexpr int NN   = 144;               // K*K*B = 3*3*16
constexpr int CC   = 32;
constexpr float LAMB  = 0.01f;
constexpr float EPSF  = 1e-6f;
constexpr float LN2PI = 1.8378770664093453f;
constexpr int NSUB = 8;                 // n-slices: 4 waves x 2 halves
constexpr int NCH  = NN / NSUB;         // 18 chunks per pass
constexpr int RST  = 36;                // sRed/sStat row stride (floats), 16B-aligned rows

__device__ __forceinline__ void mat44(const float4 pr[4], const float4 wr[4], float v[16]) {
  #pragma unroll
  for (int i = 0; i < 4; ++i) {
    v[4*i+0] = fmaf(pr[i].x, wr[0].x, fmaf(pr[i].y, wr[1].x, fmaf(pr[i].z, wr[2].x, pr[i].w * wr[3].x)));
    v[4*i+1] = fmaf(pr[i].x, wr[0].y, fmaf(pr[i].y, wr[1].y, fmaf(pr[i].z, wr[2].y, pr[i].w * wr[3].y)));
    v[4*i+2] = fmaf(pr[i].x, wr[0].z, fmaf(pr[i].y, wr[1].z, fmaf(pr[i].z, wr[2].z, pr[i].w * wr[3].z)));
    v[4*i+3] = fmaf(pr[i].x, wr[0].w, fmaf(pr[i].y, wr[1].w, fmaf(pr[i].z, wr[2].w, pr[i].w * wr[3].w)));
  }
}

__global__ __launch_bounds__(256)
void convcaps_em(const float* __restrict__ x,
                 const float* __restrict__ a,
                 const float* __restrict__ w,        // (144, 32, 4, 4)
                 const float* __restrict__ beta_u,   // (32,1)
                 const float* __restrict__ beta_a,   // (32,1)
                 const int*   __restrict__ iters_p,
                 float* __restrict__ out_mu,         // (4,14,14,32,16)
                 float* __restrict__ out_a)          // (4,14,14,32,1)
{
  __shared__ __align__(16) float sP[NN * 16];        // pose patch (broadcast reads -> no pad needed)
  __shared__ float sA[NN];                           // input activations
  __shared__ __align__(16) float sRed[4][CC][RST];   // per-wave partials: [0..15]=S1 [16..31]=S2 [32]=S0
  __shared__ __align__(16) float sStat[CC][RST];     // reduced stats per class

  const int tid = threadIdx.x;
  const int pos = blockIdx.x;
  const int b   = pos / (OHW * OHW);
  const int rem = pos - b * (OHW * OHW);
  const int oi  = rem / OHW;
  const int oj  = rem - oi * OHW;

  int iters = iters_p[0];
  iters = (iters < 1) ? 1 : (iters > 16 ? 16 : iters);

  // ---- stage pose patch + activations ----
  #pragma unroll
  for (int t = 0; t < 9; ++t) {
    const int kh = t / 3, kw = t % 3;
    sP[t * 256 + tid] = x[(((b * 16 + oi + kh) * 16) + (oj + kw)) * 256 + tid];
  }
  if (tid < NN) {
    const int kh = tid / 48, kw = (tid >> 4) % 3, bc = tid & 15;
    sA[tid] = a[(((b * 16 + oi + kh) * 16) + (oj + kw)) * 16 + bc];
  }
  __syncthreads();

  // thread map: class in lane bits 0..4 (intra-half-wave softmax via shfl_xor 1..16);
  // n-slice = wv*2 + (lane>>5); half-combine via shfl_xor 32, waves via LDS once/pass.
  const int lane = tid & 63;
  const int wv   = tid >> 6;
  const int c    = lane & 31;
  const int half = lane >> 5;
  const int sub  = wv * 2 + half;           // 0..7
  const float bu16 = 16.0f * beta_u[c];
  const float ba   = beta_a[c];

  float mu[16], hi[16], hm[16];
  float kcp = 0.f, aout = 0.f;

  for (int it = 0; it < iters; ++it) {
    float T0 = 0.f, T1[16], T2[16];
    #pragma unroll
    for (int p = 0; p < 16; ++p) { T1[p] = 0.f; T2[p] = 0.f; }

    // prefetch chunk-0 weights
    const float4* W0 = (const float4*)(w + sub * 512 + c * 16);
    float4 wr[4] = {W0[0], W0[1], W0[2], W0[3]};

    if (it == 0) {
      // ---- M0: r ~ a_in (unnormalized), no softmax ----
      #pragma unroll 1
      for (int ch = 0; ch < NCH; ++ch) {
        const int n = sub + NSUB * ch;
        const float4* Pp = (const float4*)(sP + n * 16);
        const float4 pr[4] = {Pp[0], Pp[1], Pp[2], Pp[3]};
        float v[16];
        mat44(pr, wr, v);
        if (ch < NCH - 1) {
          const float4* Wn = (const float4*)(w + (n + NSUB) * 512 + c * 16);
          wr[0] = Wn[0]; wr[1] = Wn[1]; wr[2] = Wn[2]; wr[3] = Wn[3];
        }
        const float rn = sA[n];
        T0 += rn;
        #pragma unroll
        for (int p = 0; p < 16; ++p) {
          const float rv = rn * v[p];
          T1[p] += rv;
          T2[p] = fmaf(rv, v[p], T2[p]);
        }
      }
    } else {
      // ---- fused E+M: softmax over classes entirely in-wave ----
      #pragma unroll 1
      for (int ch = 0; ch < NCH; ++ch) {
        const int n = sub + NSUB * ch;
        const float4* Pp = (const float4*)(sP + n * 16);
        const float4 pr[4] = {Pp[0], Pp[1], Pp[2], Pp[3]};
        float v[16];
        mat44(pr, wr, v);
        if (ch < NCH - 1) {
          const float4* Wn = (const float4*)(w + (n + NSUB) * 512 + c * 16);
          wr[0] = Wn[0]; wr[1] = Wn[1]; wr[2] = Wn[2]; wr[3] = Wn[3];
        }
        // s = sum_p hi*(v-mu)^2 - K  (K folded into kcp), 4-way tree
        float s0 = 0.f, s1 = 0.f, s2 = 0.f, s3 = 0.f;
        #pragma unroll
        for (int p = 0; p < 4; ++p) {
          s0 = fmaf(fmaf(hi[p],      v[p],      hm[p]),      v[p],      s0);
          s1 = fmaf(fmaf(hi[p + 4],  v[p + 4],  hm[p + 4]),  v[p + 4],  s1);
          s2 = fmaf(fmaf(hi[p + 8],  v[p + 8],  hm[p + 8]),  v[p + 8],  s2);
          s3 = fmaf(fmaf(hi[p + 12], v[p + 12], hm[p + 12]), v[p + 12], s3);
        }
        const float xv = kcp - ((s0 + s1) + (s2 + s3));
        // softmax over the 32 classes of this half-wave
        float m = xv;
        m = fmaxf(m, __shfl_xor(m, 1));
        m = fmaxf(m, __shfl_xor(m, 2));
        m = fmaxf(m, __shfl_xor(m, 4));
        m = fmaxf(m, __shfl_xor(m, 8));
        m = fmaxf(m, __shfl_xor(m, 16));
        const float e = __expf(xv - m);
        float z = e;
        z += __shfl_xor(z, 1);
        z += __shfl_xor(z, 2);
        z += __shfl_xor(z, 4);
        z += __shfl_xor(z, 8);
        z += __shfl_xor(z, 16);
        const float rn = sA[n] * e * __builtin_amdgcn_rcpf(z);
        T0 += rn;
        #pragma unroll
        for (int p = 0; p < 16; ++p) {
          const float rv = rn * v[p];
          T1[p] += rv;
          T2[p] = fmaf(rv, v[p], T2[p]);
        }
      }
    }

    // ---- combine the two halves of each wave ----
    T0 += __shfl_xor(T0, 32);
    #pragma unroll
    for (int p = 0; p < 16; ++p) {
      T1[p] += __shfl_xor(T1[p], 32);
      T2[p] += __shfl_xor(T2[p], 32);
    }

    // ---- once-per-pass cross-wave reduce (2 barriers) ----
    if (half == 0) {
      float4* d = (float4*)(&sRed[wv][c][0]);
      d[0] = make_float4(T1[0],  T1[1],  T1[2],  T1[3]);
      d[1] = make_float4(T1[4],  T1[5],  T1[6],  T1[7]);
      d[2] = make_float4(T1[8],  T1[9],  T1[10], T1[11]);
      d[3] = make_float4(T1[12], T1[13], T1[14], T1[15]);
      d[4] = make_float4(T2[0],  T2[1],  T2[2],  T2[3]);
      d[5] = make_float4(T2[4],  T2[5],  T2[6],  T2[7]);
      d[6] = make_float4(T2[8],  T2[9],  T2[10], T2[11]);
      d[7] = make_float4(T2[12], T2[13], T2[14], T2[15]);
      sRed[wv][c][32] = T0;
    }
    __syncthreads();
    {
      // 256 threads x 4 slots cover the 32x32 S1/S2 grid; lanes<32 do S0.
      const int c2 = tid & 31;
      const int s2 = tid >> 5;            // 0..7
      const float q0 = sRed[0][c2][s2]      + sRed[1][c2][s2]      + sRed[2][c2][s2]      + sRed[3][c2][s2];
      const float q1 = sRed[0][c2][s2 + 8]  + sRed[1][c2][s2 + 8]  + sRed[2][c2][s2 + 8]  + sRed[3][c2][s2 + 8];
      const float q2 = sRed[0][c2][s2 + 16] + sRed[1][c2][s2 + 16] + sRed[2][c2][s2 + 16] + sRed[3][c2][s2 + 16];
      const float q3 = sRed[0][c2][s2 + 24] + sRed[1][c2][s2 + 24] + sRed[2][c2][s2 + 24] + sRed[3][c2][s2 + 24];
      sStat[c2][s2]      = q0;
      sStat[c2][s2 + 8]  = q1;
      sStat[c2][s2 + 16] = q2;
      sStat[c2][s2 + 24] = q3;
      if (tid < 32)
        sStat[tid][32] = sRed[0][tid][32] + sRed[1][tid][32] + sRed[2][tid][32] + sRed[3][tid][32];
    }
    __syncthreads();

    // ---- per-class stats (redundant across the 8 threads sharing c) ----
    const float4* R = (const float4*)(&sStat[c][0]);
    const float4 u1a = R[0], u1b = R[1], u1c = R[2], u1d = R[3];
    const float4 u2a = R[4], u2b = R[5], u2c = R[6], u2d = R[7];
    const float U0 = sStat[c][32];
    float U1[16] = {u1a.x,u1a.y,u1a.z,u1a.w, u1b.x,u1b.y,u1b.z,u1b.w,
                    u1c.x,u1c.y,u1c.z,u1c.w, u1d.x,u1d.y,u1d.z,u1d.w};
    float U2[16] = {u2a.x,u2a.y,u2a.z,u2a.w, u2b.x,u2b.y,u2b.z,u2b.w,
                    u2c.x,u2c.y,u2c.z,u2c.w, u2d.x,u2d.y,u2d.z,u2d.w};

    // it==0: coeff = a/(sum a + 32*EPS), r_sum = U0/32; else coeff = r/(T0+EPS), r_sum = T0
    const float inv  = 1.0f / (U0 + ((it == 0) ? (CC * EPSF) : EPSF));
    const float rsum = (it == 0) ? U0 * (1.0f / CC) : U0;
    float logsum = 0.f;
    #pragma unroll
    for (int p = 0; p < 16; ++p) {
      const float m = U1[p] * inv;
      mu[p] = m;
      float sig = fmaf(m, fmaf(m, U0, -2.0f * U1[p]), U2[p]) * inv + EPSF;  // sum r(v-mu)^2 * inv + eps
      sig = fmaxf(sig, 1e-12f);
      logsum += __logf(sig);
      hi[p] = 0.5f / sig;
    }
    const float cost = rsum * (bu16 + 0.5f * logsum);
    aout = 1.0f / (1.0f + __expf(-LAMB * (ba - cost)));

    if (it < iters - 1) {
      float K = 0.f;
      #pragma unroll
      for (int p = 0; p < 16; ++p) {
        hm[p] = -2.0f * hi[p] * mu[p];
        K = fmaf(hi[p] * mu[p], mu[p], K);
      }
      kcp = __logf(aout + EPSF) - 0.5f * logsum - 8.0f * LN2PI - K;
    }
  }

  // ---- epilogue: wave 0, half 0 holds every class once ----
  if (tid < 32) {
    float4* om = (float4*)(out_mu + (size_t)pos * 512 + c * 16);
    om[0] = make_float4(mu[0],  mu[1],  mu[2],  mu[3]);
    om[1] = make_float4(mu[4],  mu[5],  mu[6],  mu[7]);
    om[2] = make_float4(mu[8],  mu[9],  mu[10], mu[11]);
    om[3] = make_float4(mu[12], mu[13], mu[14], mu[15]);
    out_a[pos * CC + c] = aout;
  }
}

} // namespace

extern "C" void kernel_launch(void* const* d_in, const int* in_sizes, int n_in,
                              void* d_out, int out_size, void* d_ws, size_t ws_size,
                              hipStream_t stream) {
  const float* x  = (const float*)d_in[0];
  const float* a  = (const float*)d_in[1];
  const float* w  = (const float*)d_in[2];
  const float* bu = (const float*)d_in[3];
  const float* ba = (const float*)d_in[4];
  const int* iters = (const int*)d_in[5];

  float* out_mu = (float*)d_out;                       // 4*14*14*32*16 = 401408
  float* out_a  = out_mu + (size_t)NPOS * CC * 16;     // + 4*14*14*32  =  25088

  convcaps_em<<<NPOS, 256, 0, stream>>>(x, a, w, bu, ba, iters, out_mu, out_a);
}

// Round 4
// 114.942 us; speedup vs baseline: 1.0863x; 1.0608x over previous
//
#include <hip/hip_runtime.h>

// ConvCaps (Matrix Capsules w/ EM routing), MI355X fp32 implementation.
// One block per output position (b, oi, oj): 784 blocks x 256 threads.
//
// v4: DPP softmax reduction. v3's counters showed the CU-shared DS pipe as
// the bottleneck: 10 serially-dependent ds_bpermute (__shfl_xor) per fused
// chunk, ~30cy each, all 12 resident waves hitting them in lockstep
// (VALUBusy 40%, HBM 1.1%, MfmaUtil 0). The 32-lane softmax allreduce is
// now done with 4 VALU DPP row_ror steps (rows of 16) + ONE ds_swizzle
// (xor-16, BitMode 0x401F) per chain: DS ops per chunk 10 -> 2, dependent
// chain ~350cy -> ~120cy. All other structure identical to v3.

namespace {

constexpr int OHW  = 14;
constexpr int NPOS = 4 * OHW * OHW;     // 784
constexpr int NN   = 144;               // K*K*B = 3*3*16
constexpr int CC   = 32;
constexpr float LAMB  = 0.01f;
constexpr float EPSF  = 1e-6f;
constexpr float LN2PI = 1.8378770664093453f;
constexpr int NSUB = 8;                 // n-slices: 4 waves x 2 halves
constexpr int NCH  = NN / NSUB;         // 18 chunks per pass
constexpr int RST  = 36;                // sRed/sStat row stride (floats), 16B-aligned rows

// DPP cross-lane move within rows of 16 (VALU, no DS). CTRL: row_ror:N = 0x120|N.
template <int CTRL>
__device__ __forceinline__ float dpp_mov(float x) {
  union { float f; int i; } u, r;
  u.f = x;
  r.i = __builtin_amdgcn_update_dpp(0, u.i, CTRL, 0xF, 0xF, true);
  return r.f;
}

// lane ^ 16 within each 32-lane group (one DS op). BitMode offset = (16<<10)|0x1F.
__device__ __forceinline__ float swz_xor16(float x) {
  union { float f; int i; } u, r;
  u.f = x;
  r.i = __builtin_amdgcn_ds_swizzle(u.i, 0x401F);
  return r.f;
}

__device__ __forceinline__ void mat44(const float4 pr[4], const float4 wr[4], float v[16]) {
  #pragma unroll
  for (int i = 0; i < 4; ++i) {
    v[4*i+0] = fmaf(pr[i].x, wr[0].x, fmaf(pr[i].y, wr[1].x, fmaf(pr[i].z, wr[2].x, pr[i].w * wr[3].x)));
    v[4*i+1] = fmaf(pr[i].x, wr[0].y, fmaf(pr[i].y, wr[1].y, fmaf(pr[i].z, wr[2].y, pr[i].w * wr[3].y)));
    v[4*i+2] = fmaf(pr[i].x, wr[0].z, fmaf(pr[i].y, wr[1].z, fmaf(pr[i].z, wr[2].z, pr[i].w * wr[3].z)));
    v[4*i+3] = fmaf(pr[i].x, wr[0].w, fmaf(pr[i].y, wr[1].w, fmaf(pr[i].z, wr[2].w, pr[i].w * wr[3].w)));
  }
}

__global__ __launch_bounds__(256)
void convcaps_em(const float* __restrict__ x,
                 const float* __restrict__ a,
                 const float* __restrict__ w,        // (144, 32, 4, 4)
                 const float* __restrict__ beta_u,   // (32,1)
                 const float* __restrict__ beta_a,   // (32,1)
                 const int*   __restrict__ iters_p,
                 float* __restrict__ out_mu,         // (4,14,14,32,16)
                 float* __restrict__ out_a)          // (4,14,14,32,1)
{
  __shared__ __align__(16) float sP[NN * 16];        // pose patch (broadcast reads)
  __shared__ float sA[NN];                           // input activations
  __shared__ __align__(16) float sRed[4][CC][RST];   // per-wave partials: [0..15]=S1 [16..31]=S2 [32]=S0
  __shared__ __align__(16) float sStat[CC][RST];     // reduced stats per class

  const int tid = threadIdx.x;
  const int pos = blockIdx.x;
  const int b   = pos / (OHW * OHW);
  const int rem = pos - b * (OHW * OHW);
  const int oi  = rem / OHW;
  const int oj  = rem - oi * OHW;

  int iters = iters_p[0];
  iters = (iters < 1) ? 1 : (iters > 16 ? 16 : iters);

  // ---- stage pose patch + activations ----
  #pragma unroll
  for (int t = 0; t < 9; ++t) {
    const int kh = t / 3, kw = t % 3;
    sP[t * 256 + tid] = x[(((b * 16 + oi + kh) * 16) + (oj + kw)) * 256 + tid];
  }
  if (tid < NN) {
    const int kh = tid / 48, kw = (tid >> 4) % 3, bc = tid & 15;
    sA[tid] = a[(((b * 16 + oi + kh) * 16) + (oj + kw)) * 16 + bc];
  }
  __syncthreads();

  // thread map: class in lane bits 0..4; n-slice = wv*2 + (lane>>5).
  const int lane = tid & 63;
  const int wv   = tid >> 6;
  const int c    = lane & 31;
  const int half = lane >> 5;
  const int sub  = wv * 2 + half;           // 0..7
  const float bu16 = 16.0f * beta_u[c];
  const float ba   = beta_a[c];

  float mu[16], hi[16], hm[16];
  float kcp = 0.f, aout = 0.f;

  for (int it = 0; it < iters; ++it) {
    float T0 = 0.f, T1[16], T2[16];
    #pragma unroll
    for (int p = 0; p < 16; ++p) { T1[p] = 0.f; T2[p] = 0.f; }

    // prefetch chunk-0 weights
    const float4* W0 = (const float4*)(w + sub * 512 + c * 16);
    float4 wr[4] = {W0[0], W0[1], W0[2], W0[3]};

    if (it == 0) {
      // ---- M0: r ~ a_in (unnormalized), no softmax ----
      #pragma unroll 1
      for (int ch = 0; ch < NCH; ++ch) {
        const int n = sub + NSUB * ch;
        const float4* Pp = (const float4*)(sP + n * 16);
        const float4 pr[4] = {Pp[0], Pp[1], Pp[2], Pp[3]};
        float v[16];
        mat44(pr, wr, v);
        if (ch < NCH - 1) {
          const float4* Wn = (const float4*)(w + (n + NSUB) * 512 + c * 16);
          wr[0] = Wn[0]; wr[1] = Wn[1]; wr[2] = Wn[2]; wr[3] = Wn[3];
        }
        const float rn = sA[n];
        T0 += rn;
        #pragma unroll
        for (int p = 0; p < 16; ++p) {
          const float rv = rn * v[p];
          T1[p] += rv;
          T2[p] = fmaf(rv, v[p], T2[p]);
        }
      }
    } else {
      // ---- fused E+M: softmax over classes, DPP + one swizzle per chain ----
      #pragma unroll 1
      for (int ch = 0; ch < NCH; ++ch) {
        const int n = sub + NSUB * ch;
        const float4* Pp = (const float4*)(sP + n * 16);
        const float4 pr[4] = {Pp[0], Pp[1], Pp[2], Pp[3]};
        float v[16];
        mat44(pr, wr, v);
        if (ch < NCH - 1) {
          const float4* Wn = (const float4*)(w + (n + NSUB) * 512 + c * 16);
          wr[0] = Wn[0]; wr[1] = Wn[1]; wr[2] = Wn[2]; wr[3] = Wn[3];
        }
        // s = sum_p hi*(v-mu)^2 - K  (K folded into kcp), 4-way tree
        float s0 = 0.f, s1 = 0.f, s2 = 0.f, s3 = 0.f;
        #pragma unroll
        for (int p = 0; p < 4; ++p) {
          s0 = fmaf(fmaf(hi[p],      v[p],      hm[p]),      v[p],      s0);
          s1 = fmaf(fmaf(hi[p + 4],  v[p + 4],  hm[p + 4]),  v[p + 4],  s1);
          s2 = fmaf(fmaf(hi[p + 8],  v[p + 8],  hm[p + 8]),  v[p + 8],  s2);
          s3 = fmaf(fmaf(hi[p + 12], v[p + 12], hm[p + 12]), v[p + 12], s3);
        }
        const float xv = kcp - ((s0 + s1) + (s2 + s3));
        // 32-lane allreduce max: 4 DPP row_ror (within-16) + 1 swizzle (xor16)
        float m = xv;
        m = fmaxf(m, dpp_mov<0x128>(m));   // ror 8
        m = fmaxf(m, dpp_mov<0x124>(m));   // ror 4
        m = fmaxf(m, dpp_mov<0x122>(m));   // ror 2
        m = fmaxf(m, dpp_mov<0x121>(m));   // ror 1
        m = fmaxf(m, swz_xor16(m));
        const float e = __expf(xv - m);
        float z = e;
        z += dpp_mov<0x128>(z);
        z += dpp_mov<0x124>(z);
        z += dpp_mov<0x122>(z);
        z += dpp_mov<0x121>(z);
        z += swz_xor16(z);
        const float rn = sA[n] * e * __builtin_amdgcn_rcpf(z);
        T0 += rn;
        #pragma unroll
        for (int p = 0; p < 16; ++p) {
          const float rv = rn * v[p];
          T1[p] += rv;
          T2[p] = fmaf(rv, v[p], T2[p]);
        }
      }
    }

    // ---- combine the two halves of each wave ----
    T0 += __shfl_xor(T0, 32);
    #pragma unroll
    for (int p = 0; p < 16; ++p) {
      T1[p] += __shfl_xor(T1[p], 32);
      T2[p] += __shfl_xor(T2[p], 32);
    }

    // ---- once-per-pass cross-wave reduce (2 barriers) ----
    if (half == 0) {
      float4* d = (float4*)(&sRed[wv][c][0]);
      d[0] = make_float4(T1[0],  T1[1],  T1[2],  T1[3]);
      d[1] = make_float4(T1[4],  T1[5],  T1[6],  T1[7]);
      d[2] = make_float4(T1[8],  T1[9],  T1[10], T1[11]);
      d[3] = make_float4(T1[12], T1[13], T1[14], T1[15]);
      d[4] = make_float4(T2[0],  T2[1],  T2[2],  T2[3]);
      d[5] = make_float4(T2[4],  T2[5],  T2[6],  T2[7]);
      d[6] = make_float4(T2[8],  T2[9],  T2[10], T2[11]);
      d[7] = make_float4(T2[12], T2[13], T2[14], T2[15]);
      sRed[wv][c][32] = T0;
    }
    __syncthreads();
    {
      // 256 threads x 4 slots cover the 32x32 S1/S2 grid; lanes<32 do S0.
      const int c2 = tid & 31;
      const int s2 = tid >> 5;            // 0..7
      const float q0 = sRed[0][c2][s2]      + sRed[1][c2][s2]      + sRed[2][c2][s2]      + sRed[3][c2][s2];
      const float q1 = sRed[0][c2][s2 + 8]  + sRed[1][c2][s2 + 8]  + sRed[2][c2][s2 + 8]  + sRed[3][c2][s2 + 8];
      const float q2 = sRed[0][c2][s2 + 16] + sRed[1][c2][s2 + 16] + sRed[2][c2][s2 + 16] + sRed[3][c2][s2 + 16];
      const float q3 = sRed[0][c2][s2 + 24] + sRed[1][c2][s2 + 24] + sRed[2][c2][s2 + 24] + sRed[3][c2][s2 + 24];
      sStat[c2][s2]      = q0;
      sStat[c2][s2 + 8]  = q1;
      sStat[c2][s2 + 16] = q2;
      sStat[c2][s2 + 24] = q3;
      if (tid < 32)
        sStat[tid][32] = sRed[0][tid][32] + sRed[1][tid][32] + sRed[2][tid][32] + sRed[3][tid][32];
    }
    __syncthreads();

    // ---- per-class stats (redundant across the 8 threads sharing c) ----
    const float4* R = (const float4*)(&sStat[c][0]);
    const float4 u1a = R[0], u1b = R[1], u1c = R[2], u1d = R[3];
    const float4 u2a = R[4], u2b = R[5], u2c = R[6], u2d = R[7];
    const float U0 = sStat[c][32];
    float U1[16] = {u1a.x,u1a.y,u1a.z,u1a.w, u1b.x,u1b.y,u1b.z,u1b.w,
                    u1c.x,u1c.y,u1c.z,u1c.w, u1d.x,u1d.y,u1d.z,u1d.w};
    float U2[16] = {u2a.x,u2a.y,u2a.z,u2a.w, u2b.x,u2b.y,u2b.z,u2b.w,
                    u2c.x,u2c.y,u2c.z,u2c.w, u2d.x,u2d.y,u2d.z,u2d.w};

    // it==0: coeff = a/(sum a + 32*EPS), r_sum = U0/32; else coeff = r/(T0+EPS), r_sum = T0
    const float inv  = 1.0f / (U0 + ((it == 0) ? (CC * EPSF) : EPSF));
    const float rsum = (it == 0) ? U0 * (1.0f / CC) : U0;
    float logsum = 0.f;
    #pragma unroll
    for (int p = 0; p < 16; ++p) {
      const float m = U1[p] * inv;
      mu[p] = m;
      float sig = fmaf(m, fmaf(m, U0, -2.0f * U1[p]), U2[p]) * inv + EPSF;  // sum r(v-mu)^2 * inv + eps
      sig = fmaxf(sig, 1e-12f);
      logsum += __logf(sig);
      hi[p] = 0.5f / sig;
    }
    const float cost = rsum * (bu16 + 0.5f * logsum);
    aout = 1.0f / (1.0f + __expf(-LAMB * (ba - cost)));

    if (it < iters - 1) {
      float K = 0.f;
      #pragma unroll
      for (int p = 0; p < 16; ++p) {
        hm[p] = -2.0f * hi[p] * mu[p];
        K = fmaf(hi[p] * mu[p], mu[p], K);
      }
      kcp = __logf(aout + EPSF) - 0.5f * logsum - 8.0f * LN2PI - K;
    }
  }

  // ---- epilogue: wave 0, half 0 holds every class once ----
  if (tid < 32) {
    float4* om = (float4*)(out_mu + (size_t)pos * 512 + c * 16);
    om[0] = make_float4(mu[0],  mu[1],  mu[2],  mu[3]);
    om[1] = make_float4(mu[4],  mu[5],  mu[6],  mu[7]);
    om[2] = make_float4(mu[8],  mu[9],  mu[10], mu[11]);
    om[3] = make_float4(mu[12], mu[13], mu[14], mu[15]);
    out_a[pos * CC + c] = aout;
  }
}

} // namespace

extern "C" void kernel_launch(void* const* d_in, const int* in_sizes, int n_in,
                              void* d_out, int out_size, void* d_ws, size_t ws_size,
                              hipStream_t stream) {
  const float* x  = (const float*)d_in[0];
  const float* a  = (const float*)d_in[1];
  const float* w  = (const float*)d_in[2];
  const float* bu = (const float*)d_in[3];
  const float* ba = (const float*)d_in[4];
  const int* iters = (const int*)d_in[5];

  float* out_mu = (float*)d_out;                       // 4*14*14*32*16 = 401408
  float* out_a  = out_mu + (size_t)NPOS * CC * 16;     // + 4*14*14*32  =  25088

  convcaps_em<<<NPOS, 256, 0, stream>>>(x, a, w, bu, ba, iters, out_mu, out_a);
}